// Round 4
// baseline (251.245 us; speedup 1.0000x reference)
//
#include <hip/hip_runtime.h>

typedef __attribute__((ext_vector_type(8))) short  short8;
typedef __attribute__((ext_vector_type(4))) short  short4v;
typedef __attribute__((ext_vector_type(4))) float  floatx4;

__device__ inline short f2bf(float f) {
    union { float f; unsigned u; } v; v.f = f;
    unsigned r = v.u + 0x7fffu + ((v.u >> 16) & 1u);
    return (short)(r >> 16);
}

typedef const __attribute__((address_space(1))) unsigned int* gp1_t;
typedef __attribute__((address_space(3))) unsigned int* lp3_t;

__device__ __attribute__((always_inline)) inline void gl_lds16(const short* g, short* l) {
    __builtin_amdgcn_global_load_lds((gp1_t)g, (lp3_t)l, 16, 0, 0);
}

// ---------------------------------------------------------------------------
// m97-style GEMM-BT core: C[128][128], 256 thr / 4 waves (2x2), BK=64.
//   C[m][n] = sum_k A[m][k] * B[n][k]
// ---------------------------------------------------------------------------
__device__ __attribute__((always_inline)) inline void gemm_bt_core(
    const short* __restrict__ Ag, const short* __restrict__ Bg,
    int lda, int ldb, int kmax,
    short* As, short* Bs, floatx4 acc[4][4])
{
    const int t    = threadIdx.x;
    const int srow = t >> 3;
    const int scol = (t & 7) * 8;
    const int lane = t & 63;
    const int wid  = t >> 6;
    const int wx   = wid & 1, wy = wid >> 1;
    const int lm   = lane & 15, lq = lane >> 4;

    for (int k0 = 0; k0 < kmax; k0 += 64) {
        __syncthreads();
#pragma unroll
        for (int i = 0; i < 4; ++i) {
            gl_lds16(Ag + (size_t)(i * 32 + srow) * lda + k0 + scol,
                     As + (i * 32 + srow) * 64 + scol);
            gl_lds16(Bg + (size_t)(i * 32 + srow) * ldb + k0 + scol,
                     Bs + (i * 32 + srow) * 64 + scol);
        }
        __syncthreads();

#pragma unroll
        for (int ks = 0; ks < 2; ++ks) {
            short8 af[4], bfr[4];
#pragma unroll
            for (int mi = 0; mi < 4; ++mi)
                af[mi] = *(const short8*)(As + (wy * 64 + mi * 16 + lm) * 64 + ks * 32 + lq * 8);
#pragma unroll
            for (int ni = 0; ni < 4; ++ni)
                bfr[ni] = *(const short8*)(Bs + (wx * 64 + ni * 16 + lm) * 64 + ks * 32 + lq * 8);
#pragma unroll
            for (int mi = 0; mi < 4; ++mi)
#pragma unroll
                for (int ni = 0; ni < 4; ++ni)
                    acc[mi][ni] = __builtin_amdgcn_mfma_f32_16x16x32_bf16(
                        af[mi], bfr[ni], acc[mi][ni], 0, 0, 0);
        }
    }
}

// ---------------------------------------------------------------------------
// Kernel 0: fp32 -> bf16 cast of x and W's.
// ---------------------------------------------------------------------------
__global__ void cast_all(const float* __restrict__ x,
                         const float* __restrict__ Wq,
                         const float* __restrict__ Wk,
                         const float* __restrict__ Wv,
                         short* __restrict__ xb, short* __restrict__ wb)
{
    size_t v = (size_t)blockIdx.x * 256 + threadIdx.x;
    const float* src; short* dst; size_t off;
    if (v < 2097152)      { src = x;  dst = xb;           off = v; }
    else if (v < 2359296) { src = Wq; dst = wb;           off = v - 2097152; }
    else if (v < 2621440) { src = Wk; dst = wb + 1048576; off = v - 2359296; }
    else if (v < 2883584) { src = Wv; dst = wb + 2097152; off = v - 2621440; }
    else return;
    floatx4 vv = ((const floatx4*)src)[off];
    short4v s;
#pragma unroll
    for (int e = 0; e < 4; ++e) s[e] = f2bf(vv[e]);
    ((short4v*)dst)[off] = s;
}

// ---------------------------------------------------------------------------
// Kernel 1: QKV projection, y = x @ W^T. Q,K row-major; V transposed [b][d][t].
// 4 blocks/CU: 60 VGPR + 64 AGPR = 124 <= 128.
// ---------------------------------------------------------------------------
__global__ __launch_bounds__(256, 4) void qkv_gemm(
    const short* __restrict__ xb, const short* __restrict__ wb,
    short* __restrict__ qb, short* __restrict__ kb, short* __restrict__ vt)
{
    __shared__ short As[128 * 64];
    __shared__ short Bs[128 * 64];

    const int m0    = blockIdx.x * 128;
    const int which = blockIdx.y >> 3;
    const int n0    = (blockIdx.y & 7) * 128;

    floatx4 acc[4][4];
    floatx4 zero = {0.f, 0.f, 0.f, 0.f};
#pragma unroll
    for (int i = 0; i < 4; ++i)
#pragma unroll
        for (int j = 0; j < 4; ++j) acc[i][j] = zero;

    gemm_bt_core(xb + (size_t)m0 * 1024,
                 wb + (size_t)blockIdx.y * 128 * 1024,
                 1024, 1024, 1024, As, Bs, acc);

    const int lane = threadIdx.x & 63, wid = threadIdx.x >> 6;
    const int wx = wid & 1, wy = wid >> 1, lm = lane & 15, lq = lane >> 4;
#pragma unroll
    for (int mi = 0; mi < 4; ++mi)
#pragma unroll
        for (int ni = 0; ni < 4; ++ni)
#pragma unroll
            for (int r = 0; r < 4; ++r) {
                int row = m0 + wy * 64 + mi * 16 + lq * 4 + r;
                int col = n0 + wx * 64 + ni * 16 + lm;
                short bvv = f2bf(acc[mi][ni][r]);
                if (which == 2) {
                    int bb = row >> 11, tt = row & 2047;
                    vt[((size_t)bb * 1024 + col) * 2048 + tt] = bvv;
                } else if (which == 1) {
                    kb[(size_t)row * 1024 + col] = bvv;
                } else {
                    qb[(size_t)row * 1024 + col] = bvv;
                }
            }
}

// ---------------------------------------------------------------------------
// Kernel 2: fused S = QK^T*scale -> P = exp(S) bf16 + causal mask.
// No max-subtraction (|s| <~ 6: e^s safe; softmax ratio exact). No row sums
// here — the denominator is recovered in pv via a ones-column MFMA.
// grid (136 packed (i,j) j<=i, 4 b). P row-major [b][q][k], ld 2048.
// ---------------------------------------------------------------------------
__global__ __launch_bounds__(256, 4) void sqk_gemm(
    const short* __restrict__ qb, const short* __restrict__ kb,
    short* __restrict__ P)
{
    int idx = blockIdx.x;
    int i = 0;
    while ((i + 1) * (i + 2) / 2 <= idx) ++i;     // decode packed (i,j)
    const int j = idx - i * (i + 1) / 2;
    const int b = blockIdx.y;

    __shared__ short As[128 * 64];
    __shared__ short Bs[128 * 64];

    floatx4 acc[4][4];
    floatx4 zero = {0.f, 0.f, 0.f, 0.f};
#pragma unroll
    for (int a = 0; a < 4; ++a)
#pragma unroll
        for (int c = 0; c < 4; ++c) acc[a][c] = zero;

    gemm_bt_core(qb + ((size_t)(b * 2048 + i * 128)) * 1024,
                 kb + ((size_t)(b * 2048 + j * 128)) * 1024,
                 1024, 1024, 1024, As, Bs, acc);

    const float sscl = 0.03125f * 1.44269504089f;   // C^-0.5 * log2(e)
    const bool  diag = (i == j);
    const int lane = threadIdx.x & 63, wid = threadIdx.x >> 6;
    const int wx = wid & 1, wy = wid >> 1, lm = lane & 15, lq = lane >> 4;

#pragma unroll
    for (int mi = 0; mi < 4; ++mi)
#pragma unroll
        for (int r = 0; r < 4; ++r) {
            const int lrow = wy * 64 + mi * 16 + lq * 4 + r;      // 0..127
            const int grow = i * 128 + lrow;
            short* prow = P + ((size_t)b * 2048 + grow) * 2048 + j * 128;
#pragma unroll
            for (int ni = 0; ni < 4; ++ni) {
                const int lcol = wx * 64 + ni * 16 + lm;
                float p = exp2f(acc[mi][ni][r] * sscl);
                if (diag && lcol > lrow) p = 0.f;                 // causal
                prow[lcol] = f2bf(p);
            }
        }
}

// ---------------------------------------------------------------------------
// Kernel 3: O = (P V) / l with l fused: acc[mi][4] = P-row-sums via an
// all-ones B fragment (D[m][n] = sum_k A[m,k]*1 for every n).
// Tile 128m x 128n, BK=64, kmax=(i+1)*128 (causal), unpaired — imbalance
// hidden by full co-residency (512 blocks <= 3/CU * 256).
// grid (8 n-tiles, 16 i, 4 b).
// ---------------------------------------------------------------------------
__global__ __launch_bounds__(256, 3) void pv_gemm(
    const short* __restrict__ P, const short* __restrict__ vt,
    float* __restrict__ out)
{
    const int x = blockIdx.x, i = blockIdx.y, b = blockIdx.z;
    const int n0 = x * 128;
    const int kmax = (i + 1) * 128;

    __shared__ short As[128 * 64];
    __shared__ short Bs[128 * 64];

    const int t    = threadIdx.x;
    const int srow = t >> 3;
    const int scol = (t & 7) * 8;
    const int lane = t & 63;
    const int wid  = t >> 6;
    const int wx   = wid & 1, wy = wid >> 1;
    const int lm   = lane & 15, lq = lane >> 4;

    const short* Ag = P  + ((size_t)b * 2048 + i * 128) * 2048;
    const short* Bg = vt + ((size_t)b * 1024 + n0) * 2048;

    floatx4 acc[4][5];                 // [mi][0..3]=O cols, [mi][4]=row sum l
    floatx4 zero = {0.f, 0.f, 0.f, 0.f};
#pragma unroll
    for (int a = 0; a < 4; ++a)
#pragma unroll
        for (int c = 0; c < 5; ++c) acc[a][c] = zero;

    short8 vones;
#pragma unroll
    for (int e = 0; e < 8; ++e) vones[e] = (short)0x3F80;   // bf16 1.0

    for (int k0 = 0; k0 < kmax; k0 += 64) {
        __syncthreads();
#pragma unroll
        for (int q = 0; q < 4; ++q) {
            gl_lds16(Ag + (size_t)(q * 32 + srow) * 2048 + k0 + scol,
                     As + (q * 32 + srow) * 64 + scol);
            gl_lds16(Bg + (size_t)(q * 32 + srow) * 2048 + k0 + scol,
                     Bs + (q * 32 + srow) * 64 + scol);
        }
        __syncthreads();

#pragma unroll
        for (int ks = 0; ks < 2; ++ks) {
            short8 af[4], bfr[4];
#pragma unroll
            for (int mi = 0; mi < 4; ++mi)
                af[mi] = *(const short8*)(As + (wy * 64 + mi * 16 + lm) * 64 + ks * 32 + lq * 8);
#pragma unroll
            for (int ni = 0; ni < 4; ++ni)
                bfr[ni] = *(const short8*)(Bs + (wx * 64 + ni * 16 + lm) * 64 + ks * 32 + lq * 8);
#pragma unroll
            for (int mi = 0; mi < 4; ++mi) {
#pragma unroll
                for (int ni = 0; ni < 4; ++ni)
                    acc[mi][ni] = __builtin_amdgcn_mfma_f32_16x16x32_bf16(
                        af[mi], bfr[ni], acc[mi][ni], 0, 0, 0);
                acc[mi][4] = __builtin_amdgcn_mfma_f32_16x16x32_bf16(
                    af[mi], vones, acc[mi][4], 0, 0, 0);
            }
        }
    }

#pragma unroll
    for (int mi = 0; mi < 4; ++mi)
#pragma unroll
        for (int r = 0; r < 4; ++r) {
            const int grow = b * 2048 + i * 128 + wy * 64 + mi * 16 + lq * 4 + r;
            const float li = 1.0f / acc[mi][4][r];
#pragma unroll
            for (int ni = 0; ni < 4; ++ni)
                out[(size_t)grow * 1024 + n0 + wx * 64 + ni * 16 + lm] =
                    acc[mi][ni][r] * li;
        }
}

// ---------------------------------------------------------------------------
extern "C" void kernel_launch(void* const* d_in, const int* in_sizes, int n_in,
                              void* d_out, int out_size, void* d_ws, size_t ws_size,
                              hipStream_t stream)
{
    (void)in_sizes; (void)n_in; (void)out_size; (void)ws_size;
    const float* x  = (const float*)d_in[0];
    const float* Wq = (const float*)d_in[1];
    const float* Wk = (const float*)d_in[2];
    const float* Wv = (const float*)d_in[3];
    float* out = (float*)d_out;

    char* base = (char*)d_ws;
    short* xb = (short*)(base);                       // 16 MB
    short* wb = (short*)(base + 16777216);            //  6 MB
    short* qb = (short*)(base + 23068672);            // 16 MB
    short* kb = (short*)(base + 39845888);            // 16 MB
    short* vt = (short*)(base + 56623104);            // 16 MB  [b][d][t]
    short* P  = (short*)(base + 73400320);            // 33.6 MB [b][q][k]
    // total ~103 MB

    cast_all<<<11264, 256, 0, stream>>>(x, Wq, Wk, Wv, xb, wb);
    qkv_gemm<<<dim3(64, 24), 256, 0, stream>>>(xb, wb, qb, kb, vt);
    sqk_gemm<<<dim3(136, 4), 256, 0, stream>>>(qb, kb, P);
    pv_gemm<<<dim3(8, 16, 4), 256, 0, stream>>>(P, vt, out);
}